// Round 2
// baseline (11274.920 us; speedup 1.0000x reference)
//
#include <hip/hip_runtime.h>
#include <cstdint>
#include <cstddef>

__device__ __forceinline__ float gelu_f(float u) {
    return 0.5f * u * (1.0f + erff(u * 0.70710678118654752f));
}

// ---------------- LayerNorm over D=512, 256 threads/row, fp32 ----------------
__global__ __launch_bounds__(256) void ln_k(const float* __restrict__ x, const float* __restrict__ w,
                                            const float* __restrict__ b, float* __restrict__ out) {
    int t = blockIdx.x, tid = threadIdx.x;
    const float* xr = x + (size_t)t * 512;
    float v0 = xr[tid], v1 = xr[tid + 256];
    float s = v0 + v1, ss = v0*v0 + v1*v1;
#pragma unroll
    for (int m = 32; m; m >>= 1) { s += __shfl_xor(s, m); ss += __shfl_xor(ss, m); }
    __shared__ float red[8];
    int wv = tid >> 6;
    if ((tid & 63) == 0) { red[wv] = s; red[4 + wv] = ss; }
    __syncthreads();
    s  = red[0] + red[1] + red[2] + red[3];
    ss = red[4] + red[5] + red[6] + red[7];
    float mean = s * (1.f/512.f);
    float var  = ss * (1.f/512.f) - mean * mean;
    float rstd = rsqrtf(var + 1e-5f);
    out[(size_t)t*512 + tid]       = (v0 - mean) * rstd * w[tid]       + b[tid];
    out[(size_t)t*512 + tid + 256] = (v1 - mean) * rstd * w[tid + 256] + b[tid + 256];
}

// ---------------- fp32 SGEMM: C[M,N] = A[M,K] @ B[K,N]  (128x128 tile, BK=16, 8x8 microtile) ----
// EPI: 0 = store f32; 2 = gelu(acc+bias); 3 = C += acc + bias (residual); 4 = acc + bias; 5 = C += acc
template<int EPI>
__global__ __launch_bounds__(256) void sgemm(
    const float* __restrict__ A, int lda,
    const float* __restrict__ B, int ldb,      // B row-major [K][N], row stride ldb
    const float* __restrict__ bias,
    float* __restrict__ C, int ldc,
    int M, int K,
    const int* __restrict__ cnts, const int* __restrict__ offs,
    long bStrideZ, long biasStrideZ)
{
    int e = blockIdx.z;
    int mcnt = M;
    if (cnts) {
        mcnt = cnts[e];
        if ((int)(blockIdx.x * 128) >= mcnt) return;
        long ao = offs[e];
        A += (size_t)ao * lda;
        C += (size_t)ao * ldc;
        B += (size_t)e * bStrideZ;
        if (bias) bias += (size_t)e * biasStrideZ;
    } else if ((int)(blockIdx.x * 128) >= mcnt) return;

    const int m0 = blockIdx.x * 128, n0 = blockIdx.y * 128;
    const int t = threadIdx.x;
    const int ti = t & 15, tj = t >> 4;       // microtile: rows ti*8.., cols tj*8..

    __shared__ float As[16][132];
    __shared__ float Bs[16][128];

    float c[8][8] = {};

    const int ar  = t >> 2;                    // 0..63
    const int ac4 = (t & 3) * 4;               // k offset within BK
    const int bk  = t >> 5;                    // 0..7
    const int bn4 = (t & 31) * 4;

    int arow0 = m0 + ar;      if (arow0 >= mcnt) arow0 = mcnt - 1;
    int arow1 = m0 + ar + 64; if (arow1 >= mcnt) arow1 = mcnt - 1;
    const float* a0 = A + (size_t)arow0 * lda + ac4;
    const float* a1 = A + (size_t)arow1 * lda + ac4;
    const float* b0 = B + (size_t)bk * ldb + n0 + bn4;
    const float* b1 = B + (size_t)(bk + 8) * ldb + n0 + bn4;

    for (int k0 = 0; k0 < K; k0 += 16) {
        __syncthreads();
        float4 av0 = *(const float4*)(a0 + k0);
        float4 av1 = *(const float4*)(a1 + k0);
        float4 bv0 = *(const float4*)(b0 + (size_t)k0 * ldb);
        float4 bv1 = *(const float4*)(b1 + (size_t)k0 * ldb);
        As[ac4+0][ar]      = av0.x; As[ac4+1][ar]      = av0.y;
        As[ac4+2][ar]      = av0.z; As[ac4+3][ar]      = av0.w;
        As[ac4+0][ar+64]   = av1.x; As[ac4+1][ar+64]   = av1.y;
        As[ac4+2][ar+64]   = av1.z; As[ac4+3][ar+64]   = av1.w;
        *(float4*)&Bs[bk][bn4]     = bv0;
        *(float4*)&Bs[bk+8][bn4]   = bv1;
        __syncthreads();
#pragma unroll
        for (int k = 0; k < 16; k++) {
            float a[8], bb[8];
            *(float4*)&a[0]  = *(const float4*)&As[k][ti*8];
            *(float4*)&a[4]  = *(const float4*)&As[k][ti*8 + 4];
            *(float4*)&bb[0] = *(const float4*)&Bs[k][tj*8];
            *(float4*)&bb[4] = *(const float4*)&Bs[k][tj*8 + 4];
#pragma unroll
            for (int r = 0; r < 8; r++)
#pragma unroll
                for (int cc = 0; cc < 8; cc++)
                    c[r][cc] = fmaf(a[r], bb[cc], c[r][cc]);
        }
    }

#pragma unroll
    for (int r = 0; r < 8; r++) {
        int row = m0 + ti*8 + r;
        if (row >= mcnt) continue;
        float* crow = C + (size_t)row * ldc + n0 + tj*8;
#pragma unroll
        for (int h4 = 0; h4 < 2; h4++) {
            float4 v = *(float4*)&c[r][h4*4];
            int colb = n0 + tj*8 + h4*4;
            if (EPI == 0) {
                *(float4*)(crow + h4*4) = v;
            } else if (EPI == 2) {
                float4 bb = *(const float4*)(bias + colb);
                float4 o;
                o.x = gelu_f(v.x + bb.x); o.y = gelu_f(v.y + bb.y);
                o.z = gelu_f(v.z + bb.z); o.w = gelu_f(v.w + bb.w);
                *(float4*)(crow + h4*4) = o;
            } else if (EPI == 3) {
                float4 bb = *(const float4*)(bias + colb);
                float4 old = *(float4*)(crow + h4*4);
                old.x += v.x + bb.x; old.y += v.y + bb.y;
                old.z += v.z + bb.z; old.w += v.w + bb.w;
                *(float4*)(crow + h4*4) = old;
            } else if (EPI == 4) {
                float4 bb = *(const float4*)(bias + colb);
                float4 o;
                o.x = v.x + bb.x; o.y = v.y + bb.y; o.z = v.z + bb.z; o.w = v.w + bb.w;
                *(float4*)(crow + h4*4) = o;
            } else {
                float4 old = *(float4*)(crow + h4*4);
                old.x += v.x; old.y += v.y; old.z += v.z; old.w += v.w;
                *(float4*)(crow + h4*4) = old;
            }
        }
    }
}

// ---------------- fp32 flash attention: grid (16 q-tiles, 64 bh), block 256 ----------------
__global__ __launch_bounds__(256) void attn32_k(const float* __restrict__ qkvb, float* __restrict__ obuf) {
    const int qt = blockIdx.x, bh = blockIdx.y;
    const int b = bh >> 3, h = bh & 7;
    const int t = threadIdx.x;
    const int tx = t & 15, ty = t >> 4;

    __shared__ float Qs[64][72], KVs[64][72], Ss[64][72];
    __shared__ float mrow[64], lrow[64], arow[64];

    const int   srow = t >> 2;
    const int   sc0  = (t & 3) * 16;
    const float* qbase = qkvb + ((size_t)b*1024 + (size_t)qt*64) * 1536 + h*64;
    {
        const float* src = qbase + (size_t)srow * 1536 + sc0;
        *(float4*)&Qs[srow][sc0]      = *(const float4*)(src);
        *(float4*)&Qs[srow][sc0 + 4]  = *(const float4*)(src + 4);
        *(float4*)&Qs[srow][sc0 + 8]  = *(const float4*)(src + 8);
        *(float4*)&Qs[srow][sc0 + 12] = *(const float4*)(src + 12);
    }
    if (t < 64) { mrow[t] = -INFINITY; lrow[t] = 0.f; }

    float o[4][4] = {};
    const float* kbase = qkvb + (size_t)b * 1024 * 1536 + 512  + h*64;
    const float* vbase = qkvb + (size_t)b * 1024 * 1536 + 1024 + h*64;

    for (int kv0 = 0; kv0 < 1024; kv0 += 64) {
        __syncthreads();   // protect KVs/Ss reuse from previous iteration
        {
            const float* src = kbase + (size_t)(kv0 + srow) * 1536 + sc0;
            *(float4*)&KVs[srow][sc0]      = *(const float4*)(src);
            *(float4*)&KVs[srow][sc0 + 4]  = *(const float4*)(src + 4);
            *(float4*)&KVs[srow][sc0 + 8]  = *(const float4*)(src + 8);
            *(float4*)&KVs[srow][sc0 + 12] = *(const float4*)(src + 12);
        }
        __syncthreads();
        float s[4][4] = {};
#pragma unroll
        for (int d4 = 0; d4 < 16; d4++) {
            float4 qv[4], kv[4];
#pragma unroll
            for (int r = 0; r < 4; r++) qv[r] = *(const float4*)&Qs[ty*4 + r][d4*4];
#pragma unroll
            for (int cc = 0; cc < 4; cc++) kv[cc] = *(const float4*)&KVs[tx*4 + cc][d4*4];
#pragma unroll
            for (int r = 0; r < 4; r++)
#pragma unroll
                for (int cc = 0; cc < 4; cc++)
                    s[r][cc] += qv[r].x*kv[cc].x + qv[r].y*kv[cc].y + qv[r].z*kv[cc].z + qv[r].w*kv[cc].w;
        }
#pragma unroll
        for (int r = 0; r < 4; r++)
#pragma unroll
            for (int cc = 0; cc < 4; cc++)
                Ss[ty*4 + r][tx*4 + cc] = s[r][cc] * 0.125f;
        __syncthreads();
        if (t < 64) {
            float mold = mrow[t];
            float mx = mold;
#pragma unroll 8
            for (int j = 0; j < 64; j++) mx = fmaxf(mx, Ss[t][j]);
            float a = __expf(mold - mx);
            float sum = 0.f;
#pragma unroll 8
            for (int j = 0; j < 64; j++) {
                float p = __expf(Ss[t][j] - mx);
                Ss[t][j] = p;
                sum += p;
            }
            mrow[t] = mx;
            lrow[t] = lrow[t] * a + sum;
            arow[t] = a;
        }
        __syncthreads();
        {
            const float* src = vbase + (size_t)(kv0 + srow) * 1536 + sc0;
            *(float4*)&KVs[srow][sc0]      = *(const float4*)(src);
            *(float4*)&KVs[srow][sc0 + 4]  = *(const float4*)(src + 4);
            *(float4*)&KVs[srow][sc0 + 8]  = *(const float4*)(src + 8);
            *(float4*)&KVs[srow][sc0 + 12] = *(const float4*)(src + 12);
        }
        float al[4];
#pragma unroll
        for (int r = 0; r < 4; r++) al[r] = arow[ty*4 + r];
#pragma unroll
        for (int r = 0; r < 4; r++)
#pragma unroll
            for (int cc = 0; cc < 4; cc++)
                o[r][cc] *= al[r];
        __syncthreads();
#pragma unroll 4
        for (int j4 = 0; j4 < 16; j4++) {
            float4 pv[4], vv[4];
#pragma unroll
            for (int r = 0; r < 4; r++) pv[r] = *(const float4*)&Ss[ty*4 + r][j4*4];
#pragma unroll
            for (int jj = 0; jj < 4; jj++) vv[jj] = *(const float4*)&KVs[j4*4 + jj][tx*4];
#pragma unroll
            for (int r = 0; r < 4; r++) {
                o[r][0] += pv[r].x*vv[0].x + pv[r].y*vv[1].x + pv[r].z*vv[2].x + pv[r].w*vv[3].x;
                o[r][1] += pv[r].x*vv[0].y + pv[r].y*vv[1].y + pv[r].z*vv[2].y + pv[r].w*vv[3].y;
                o[r][2] += pv[r].x*vv[0].z + pv[r].y*vv[1].z + pv[r].z*vv[2].z + pv[r].w*vv[3].z;
                o[r][3] += pv[r].x*vv[0].w + pv[r].y*vv[1].w + pv[r].z*vv[2].w + pv[r].w*vv[3].w;
            }
        }
    }
    float linv[4];
#pragma unroll
    for (int r = 0; r < 4; r++) linv[r] = 1.f / lrow[ty*4 + r];
#pragma unroll
    for (int r = 0; r < 4; r++) {
        size_t row = (size_t)b*1024 + (size_t)qt*64 + ty*4 + r;
        float* dst = obuf + row * 512 + h*64 + tx*4;
        dst[0] = o[r][0]*linv[r]; dst[1] = o[r][1]*linv[r];
        dst[2] = o[r][2]*linv[r]; dst[3] = o[r][3]*linv[r];
    }
}

// ---------------- gating: fp32 logits from xn + top-2 softmax (one wave / token) ----------------
__global__ __launch_bounds__(64) void gating_k(const float* __restrict__ xn, const float* __restrict__ wg,
                                               int* __restrict__ top_i, float* __restrict__ top_g,
                                               int* __restrict__ counts) {
    int t = blockIdx.x, lane = threadIdx.x;
    const float* xr = xn + (size_t)t * 512;
    float acc[8] = {};
#pragma unroll
    for (int i = 0; i < 8; i++) {
        int d = lane + i*64;
        float xv = xr[d];
        const float* wrow = wg + (size_t)d * 8;
#pragma unroll
        for (int e = 0; e < 8; e++) acc[e] += xv * wrow[e];
    }
#pragma unroll
    for (int e = 0; e < 8; e++)
#pragma unroll
        for (int m = 32; m; m >>= 1) acc[e] += __shfl_xor(acc[e], m);
    if (lane == 0) {
        int e0 = 0; float v0 = acc[0];
        for (int e = 1; e < 8; e++) if (acc[e] > v0) { v0 = acc[e]; e0 = e; }
        int e1 = -1; float v1 = -INFINITY;
        for (int e = 0; e < 8; e++) if (e != e0 && acc[e] > v1) { v1 = acc[e]; e1 = e; }
        float g0 = 1.f / (1.f + expf(v1 - v0));
        top_i[2*t] = e0; top_i[2*t + 1] = e1;
        top_g[2*t] = g0; top_g[2*t + 1] = 1.f - g0;
        atomicAdd(&counts[e0], 1);
        atomicAdd(&counts[e1], 1);
    }
}

__global__ void zero_counts_k(int* counts) { if (threadIdx.x < 8) counts[threadIdx.x] = 0; }

__global__ void offsets_k(const int* __restrict__ counts, int* __restrict__ offs, int* __restrict__ cursor) {
    if (threadIdx.x == 0) {
        int o = 0;
        for (int e = 0; e < 8; e++) { offs[e] = o; cursor[e] = o; o += counts[e]; }
    }
}

__global__ __launch_bounds__(256) void scatter_k(const int* __restrict__ top_i, int* __restrict__ cursor,
                                                 int* __restrict__ assign_token, int* __restrict__ assign_slot) {
    int t = blockIdx.x * 256 + threadIdx.x;
#pragma unroll
    for (int k = 0; k < 2; k++) {
        int e = top_i[2*t + k];
        int pos = atomicAdd(&cursor[e], 1);
        assign_token[pos] = t;
        assign_slot[2*t + k] = pos;
    }
}

__global__ __launch_bounds__(64) void gather_k(const float* __restrict__ xn, const int* __restrict__ assign_token,
                                               float* __restrict__ xe) {
    int a = blockIdx.x, lane = threadIdx.x;
    int t = assign_token[a];
    const float4* src = (const float4*)(xn + (size_t)t * 512);
    float4* dst = (float4*)(xe + (size_t)a * 512);
    dst[lane]      = src[lane];
    dst[lane + 64] = src[lane + 64];
}

__global__ __launch_bounds__(64) void combine_k(float* __restrict__ x, const float* __restrict__ y,
                                                const int* __restrict__ assign_slot, const float* __restrict__ top_g) {
    int t = blockIdx.x, lane = threadIdx.x;
    int p0 = assign_slot[2*t], p1 = assign_slot[2*t + 1];
    float g0 = top_g[2*t], g1 = top_g[2*t + 1];
    float4* xr = (float4*)(x + (size_t)t * 512);
    const float4* y0 = (const float4*)(y + (size_t)p0 * 512);
    const float4* y1 = (const float4*)(y + (size_t)p1 * 512);
#pragma unroll
    for (int i = 0; i < 2; i++) {
        int idx = lane + i * 64;
        float4 a = xr[idx], c0 = y0[idx], c1 = y1[idx];
        a.x += g0*c0.x + g1*c1.x; a.y += g0*c0.y + g1*c1.y;
        a.z += g0*c0.z + g1*c1.z; a.w += g0*c0.w + g1*c1.w;
        xr[idx] = a;
    }
}

extern "C" void kernel_launch(void* const* d_in, const int* in_sizes, int n_in,
                              void* d_out, int out_size, void* d_ws, size_t ws_size,
                              hipStream_t stream) {
    const float* x_in = (const float*)d_in[0];
    const float* ln1w = (const float*)d_in[1];
    const float* ln1b = (const float*)d_in[2];
    const float* qkvw = (const float*)d_in[3];
    const float* outw = (const float*)d_in[4];
    const float* outb = (const float*)d_in[5];
    const float* ln2w = (const float*)d_in[6];
    const float* ln2b = (const float*)d_in[7];
    const float* wg   = (const float*)d_in[8];
    const float* ew1  = (const float*)d_in[9];
    const float* eb1  = (const float*)d_in[10];
    const float* ew2  = (const float*)d_in[11];
    const float* eb2  = (const float*)d_in[12];
    const float* flnw = (const float*)d_in[13];
    const float* flnb = (const float*)d_in[14];

    float* x = (float*)d_out;                       // residual [8192,512] f32

    char* ws = (char*)d_ws;
    float* xn   = (float*)(ws + 0);                 // [8192,512]   16.0 MB
    char*  S    = ws + 16777216;                    // phase-shared region
    // attn phase
    float* qkvb = (float*)(S + 0);                  // [8192,1536]  48.0 MB
    float* obuf = (float*)(S + 50331648);           // [8192,512]   16.0 MB
    // moe phase (reuses S)
    float* xe   = (float*)(S + 0);                  // [16384,512]  32.0 MB
    float* hbuf = (float*)(S + 33554432);           // [16384,512]  32.0 MB (per H-slice)
    float* ybuf = (float*)(S + 67108864);           // [16384,512]  32.0 MB
    char*  SM   = ws + 16777216 + 100663296;
    int*   top_i        = (int*)(SM + 0);
    float* top_g        = (float*)(SM + 65536);
    int*   assign_token = (int*)(SM + 131072);
    int*   assign_slot  = (int*)(SM + 196608);
    int*   counts       = (int*)(SM + 262144);
    int*   offs         = (int*)(SM + 262400);
    int*   cursor       = (int*)(SM + 262656);

    hipMemcpyAsync(x, x_in, (size_t)8192 * 512 * 4, hipMemcpyDeviceToDevice, stream);

    for (int l = 0; l < 4; l++) {
        const float* qkvw_l = qkvw + (size_t)l * 512 * 1536;
        const float* outw_l = outw + (size_t)l * 512 * 512;
        const float* ew1_l  = ew1  + (size_t)l * 8 * 512 * 2048;
        const float* ew2_l  = ew2  + (size_t)l * 8 * 2048 * 512;
        const float* eb1_l  = eb1  + (size_t)l * 8 * 2048;
        const float* eb2_l  = eb2  + (size_t)l * 8 * 512;

        // ---- attention ----
        ln_k<<<8192, 256, 0, stream>>>(x, ln1w + l*512, ln1b + l*512, xn);
        sgemm<0><<<dim3(64, 12, 1), 256, 0, stream>>>(xn, 512, qkvw_l, 1536, nullptr,
                                                      qkvb, 1536, 8192, 512,
                                                      nullptr, nullptr, 0, 0);
        attn32_k<<<dim3(16, 64), 256, 0, stream>>>(qkvb, obuf);
        sgemm<3><<<dim3(64, 4, 1), 256, 0, stream>>>(obuf, 512, outw_l, 512, outb + l*512,
                                                     x, 512, 8192, 512,
                                                     nullptr, nullptr, 0, 0);

        // ---- MoE ----
        ln_k<<<8192, 256, 0, stream>>>(x, ln2w + l*512, ln2b + l*512, xn);
        zero_counts_k<<<1, 64, 0, stream>>>(counts);
        gating_k<<<8192, 64, 0, stream>>>(xn, wg + (size_t)l*512*8, top_i, top_g, counts);
        offsets_k<<<1, 1, 0, stream>>>(counts, offs, cursor);
        scatter_k<<<32, 256, 0, stream>>>(top_i, cursor, assign_token, assign_slot);
        gather_k<<<16384, 64, 0, stream>>>(xn, assign_token, xe);

        for (int s = 0; s < 4; s++) {
            const float* b1slice = ew1_l + (size_t)s * 512;          // columns h_off..h_off+511
            const float* b2slice = ew2_l + (size_t)s * 512 * 512;    // k-rows  h_off..h_off+511
            sgemm<2><<<dim3(64, 4, 8), 256, 0, stream>>>(xe, 512, b1slice, 2048, eb1_l + s*512,
                                                         hbuf, 512, 0, 512,
                                                         counts, offs,
                                                         (long)512*2048, 2048);
            if (s == 0)
                sgemm<4><<<dim3(64, 4, 8), 256, 0, stream>>>(hbuf, 512, b2slice, 512, eb2_l,
                                                             ybuf, 512, 0, 512,
                                                             counts, offs,
                                                             (long)2048*512, 512);
            else
                sgemm<5><<<dim3(64, 4, 8), 256, 0, stream>>>(hbuf, 512, b2slice, 512, nullptr,
                                                             ybuf, 512, 0, 512,
                                                             counts, offs,
                                                             (long)2048*512, 512);
        }
        combine_k<<<8192, 64, 0, stream>>>(x, ybuf, assign_slot, top_g);
    }
    ln_k<<<8192, 256, 0, stream>>>(x, flnw, flnb, x);
}

// Round 3
// 7099.429 us; speedup vs baseline: 1.5881x; 1.5881x over previous
//
#include <hip/hip_runtime.h>
#include <cstdint>
#include <cstddef>

typedef unsigned short u16;
typedef unsigned int   u32;
typedef _Float16       f16;

typedef float f32x4 __attribute__((ext_vector_type(4)));
typedef _Float16 f16x8 __attribute__((ext_vector_type(8)));

#define MB (1024u*1024u)
#define RCP2048 (1.0f/2048.0f)

__device__ __forceinline__ float gelu_f(float u) {
    return 0.5f * u * (1.0f + erff(u * 0.70710678118654752f));
}

__device__ __forceinline__ void split_f(float v, f16* hi, f16* lo) {
    f16 h = (f16)v;
    *hi = h;
    *lo = (f16)((v - (float)h) * 2048.0f);
}

__device__ __forceinline__ void gload_lds16(const f16* g, f16* l) {
    __builtin_amdgcn_global_load_lds((const __attribute__((address_space(1))) u32*)(g),
                                     (__attribute__((address_space(3))) u32*)(l), 16, 0, 0);
}

// ---------------- transpose + split: in [R][C] f32 -> hi/lo fp16 [C][R] ----------------
__global__ void transpose_split_k(const float* __restrict__ in, f16* __restrict__ oh, f16* __restrict__ ol,
                                  int R, int C, long bsi, long bso) {
    __shared__ float tile[32][33];
    int z = blockIdx.z;
    in += (size_t)z * bsi; oh += (size_t)z * bso; ol += (size_t)z * bso;
    int c0 = blockIdx.x * 32, r0 = blockIdx.y * 32;
    int tx = threadIdx.x, ty = threadIdx.y;   // (32,8)
#pragma unroll
    for (int i = 0; i < 4; i++)
        tile[ty + i*8][tx] = in[(size_t)(r0 + ty + i*8) * C + c0 + tx];
    __syncthreads();
#pragma unroll
    for (int i = 0; i < 4; i++) {
        float v = tile[tx][ty + i*8];
        f16 h, l; split_f(v, &h, &l);
        size_t o = (size_t)(c0 + ty + i*8) * R + r0 + tx;
        oh[o] = h; ol[o] = l;
    }
}

// ---------------- f16 plane transpose (for V): src[t][1536] col-block -> vt[bh][d][n] ----------------
__global__ void transpose_v_k(const f16* __restrict__ plane, f16* __restrict__ vt) {
    __shared__ f16 tile[32][33];
    int bh = blockIdx.z; int b = bh >> 3, h = bh & 7;
    int n0 = blockIdx.x * 32, d0 = blockIdx.y * 32;
    int tx = threadIdx.x, ty = threadIdx.y;   // (32,8)
    const f16* src = plane + (size_t)b * 1024 * 1536 + 1024 + h * 64;
#pragma unroll
    for (int i = 0; i < 4; i++)
        tile[ty + i*8][tx] = src[(size_t)(n0 + ty + i*8) * 1536 + d0 + tx];
    __syncthreads();
    f16* dst = vt + (size_t)bh * 64 * 1024;
#pragma unroll
    for (int i = 0; i < 4; i++)
        dst[(size_t)(d0 + ty + i*8) * 1024 + n0 + tx] = tile[tx][ty + i*8];
}

// ---------------- LayerNorm: fp32 in -> optional fp32 out + hi/lo fp16 planes ----------------
template<int W32>
__global__ __launch_bounds__(256) void ln_split_k(const float* __restrict__ x, const float* __restrict__ w,
                                                  const float* __restrict__ b, float* __restrict__ o32,
                                                  f16* __restrict__ oh, f16* __restrict__ ol) {
    int t = blockIdx.x, tid = threadIdx.x;
    const float* xr = x + (size_t)t * 512;
    float v0 = xr[tid], v1 = xr[tid + 256];
    float s = v0 + v1, ss = v0*v0 + v1*v1;
#pragma unroll
    for (int m = 32; m; m >>= 1) { s += __shfl_xor(s, m); ss += __shfl_xor(ss, m); }
    __shared__ float red[8];
    int wv = tid >> 6;
    if ((tid & 63) == 0) { red[wv] = s; red[4 + wv] = ss; }
    __syncthreads();
    s  = red[0] + red[1] + red[2] + red[3];
    ss = red[4] + red[5] + red[6] + red[7];
    float mean = s * (1.f/512.f);
    float var  = ss * (1.f/512.f) - mean * mean;
    float rstd = rsqrtf(var + 1e-5f);
    float u0 = (v0 - mean) * rstd * w[tid]       + b[tid];
    float u1 = (v1 - mean) * rstd * w[tid + 256] + b[tid + 256];
    size_t base = (size_t)t * 512;
    if (W32) { o32[base + tid] = u0; o32[base + tid + 256] = u1; }
    f16 h0, l0, h1, l1;
    split_f(u0, &h0, &l0); split_f(u1, &h1, &l1);
    oh[base + tid] = h0; ol[base + tid] = l0;
    oh[base + tid + 256] = h1; ol[base + tid + 256] = l1;
}

// ---------------- plain fp32 LayerNorm (final) ----------------
__global__ __launch_bounds__(256) void ln_k(const float* __restrict__ x, const float* __restrict__ w,
                                            const float* __restrict__ b, float* __restrict__ out) {
    int t = blockIdx.x, tid = threadIdx.x;
    const float* xr = x + (size_t)t * 512;
    float v0 = xr[tid], v1 = xr[tid + 256];
    float s = v0 + v1, ss = v0*v0 + v1*v1;
#pragma unroll
    for (int m = 32; m; m >>= 1) { s += __shfl_xor(s, m); ss += __shfl_xor(ss, m); }
    __shared__ float red[8];
    int wv = tid >> 6;
    if ((tid & 63) == 0) { red[wv] = s; red[4 + wv] = ss; }
    __syncthreads();
    s  = red[0] + red[1] + red[2] + red[3];
    ss = red[4] + red[5] + red[6] + red[7];
    float mean = s * (1.f/512.f);
    float var  = ss * (1.f/512.f) - mean * mean;
    float rstd = rsqrtf(var + 1e-5f);
    out[(size_t)t*512 + tid]       = (v0 - mean) * rstd * w[tid]       + b[tid];
    out[(size_t)t*512 + tid + 256] = (v1 - mean) * rstd * w[tid + 256] + b[tid + 256];
}

// ---------------- split-fp16 MFMA GEMM: C = (Ah+Al/2048) @ (Bh+Bl/2048)^T ----------------
// A[M,K] hi/lo, Bt[N,K] hi/lo. 128x128 tile, BK=32, 3 MFMA products.
// EPI: 0 = split-store fp16 hi/lo; 1 = fp32 C += acc + bias; 2 = gelu(acc+bias) split-store;
//      3 = fp32 C = acc + bias; 4 = fp32 C += acc
template<int EPI>
__global__ __launch_bounds__(256) void gemm_sp(
    const f16* __restrict__ Ah, const f16* __restrict__ Al, int lda,
    const f16* __restrict__ Bh, const f16* __restrict__ Bl, int ldb,
    const float* __restrict__ bias,
    void* __restrict__ C0v, void* __restrict__ C1v, int ldc,
    int M, int K,
    const int* __restrict__ cnts, const int* __restrict__ offs,
    long bStrideZ, long biasStrideZ)
{
    int e = blockIdx.z;
    int mcnt = M;
    long aoff = 0;
    if (cnts) {
        mcnt = cnts[e];
        if ((int)(blockIdx.x * 128) >= mcnt) return;
        aoff = offs[e];
        Ah += (size_t)aoff * lda; Al += (size_t)aoff * lda;
        Bh += (size_t)e * bStrideZ; Bl += (size_t)e * bStrideZ;
        if (bias) bias += (size_t)e * biasStrideZ;
    } else if ((int)(blockIdx.x * 128) >= mcnt) return;

    f16*   C0h = (f16*)C0v   + (size_t)aoff * ldc;
    f16*   C1l = (f16*)C1v   + (size_t)aoff * ldc;
    float* Cf  = (float*)C0v + (size_t)aoff * ldc;

    const int m0 = blockIdx.x * 128, n0 = blockIdx.y * 128;
    const int tid  = threadIdx.x;
    const int wave = tid >> 6, lane = tid & 63;
    const int quad = lane >> 4, l15 = lane & 15;
    const int wr = (wave >> 1) * 64, wc = (wave & 1) * 64;

    __shared__ __align__(16) f16 Ash[4096];
    __shared__ __align__(16) f16 Asl[4096];
    __shared__ __align__(16) f16 Bsh[4096];
    __shared__ __align__(16) f16 Bsl[4096];

    f32x4 acc[4][4] = {};
    f32x4 ac2[4][4] = {};

    const int la = tid * 8;
    const int ra = tid >> 2, ca = (tid & 3) * 8;
    int r0a = m0 + ra;        if (r0a > mcnt - 1) r0a = mcnt - 1;
    int r1a = m0 + ra + 64;   if (r1a > mcnt - 1) r1a = mcnt - 1;
    const f16* ah0 = Ah + (size_t)r0a * lda + ca;
    const f16* ah1 = Ah + (size_t)r1a * lda + ca;
    const f16* al0 = Al + (size_t)r0a * lda + ca;
    const f16* al1 = Al + (size_t)r1a * lda + ca;
    const f16* bh0 = Bh + (size_t)(n0 + ra) * ldb + ca;
    const f16* bh1 = Bh + (size_t)(n0 + ra + 64) * ldb + ca;
    const f16* bl0 = Bl + (size_t)(n0 + ra) * ldb + ca;
    const f16* bl1 = Bl + (size_t)(n0 + ra + 64) * ldb + ca;

    for (int k0 = 0; k0 < K; k0 += 32) {
        __syncthreads();
        gload_lds16(ah0 + k0, &Ash[la]);
        gload_lds16(ah1 + k0, &Ash[2048 + la]);
        gload_lds16(al0 + k0, &Asl[la]);
        gload_lds16(al1 + k0, &Asl[2048 + la]);
        gload_lds16(bh0 + k0, &Bsh[la]);
        gload_lds16(bh1 + k0, &Bsh[2048 + la]);
        gload_lds16(bl0 + k0, &Bsl[la]);
        gload_lds16(bl1 + k0, &Bsl[2048 + la]);
        __syncthreads();
        f16x8 afh[4], afl[4], bfh[4], bfl[4];
#pragma unroll
        for (int mi = 0; mi < 4; mi++) {
            int ro = (wr + mi*16 + l15) * 32 + quad * 8;
            afh[mi] = *(const f16x8*)&Ash[ro];
            afl[mi] = *(const f16x8*)&Asl[ro];
        }
#pragma unroll
        for (int ni = 0; ni < 4; ni++) {
            int ro = (wc + ni*16 + l15) * 32 + quad * 8;
            bfh[ni] = *(const f16x8*)&Bsh[ro];
            bfl[ni] = *(const f16x8*)&Bsl[ro];
        }
#pragma unroll
        for (int mi = 0; mi < 4; mi++)
#pragma unroll
            for (int ni = 0; ni < 4; ni++) {
                acc[mi][ni] = __builtin_amdgcn_mfma_f32_16x16x32_f16(afh[mi], bfh[ni], acc[mi][ni], 0, 0, 0);
                ac2[mi][ni] = __builtin_amdgcn_mfma_f32_16x16x32_f16(afh[mi], bfl[ni], ac2[mi][ni], 0, 0, 0);
                ac2[mi][ni] = __builtin_amdgcn_mfma_f32_16x16x32_f16(afl[mi], bfh[ni], ac2[mi][ni], 0, 0, 0);
            }
    }

#pragma unroll
    for (int mi = 0; mi < 4; mi++) {
#pragma unroll
        for (int r = 0; r < 4; r++) {
            int row = m0 + wr + mi*16 + quad*4 + r;
            if (row >= mcnt) continue;
            size_t ro = (size_t)row * ldc;
#pragma unroll
            for (int ni = 0; ni < 4; ni++) {
                int col = n0 + wc + ni*16 + l15;
                float v = acc[mi][ni][r] + ac2[mi][ni][r] * RCP2048;
                if (EPI == 0) {
                    f16 h, l; split_f(v, &h, &l);
                    C0h[ro + col] = h; C1l[ro + col] = l;
                } else if (EPI == 1) {
                    Cf[ro + col] += v + bias[col];
                } else if (EPI == 2) {
                    float g = gelu_f(v + bias[col]);
                    f16 h, l; split_f(g, &h, &l);
                    C0h[ro + col] = h; C1l[ro + col] = l;
                } else if (EPI == 3) {
                    Cf[ro + col] = v + bias[col];
                } else {
                    Cf[ro + col] += v;
                }
            }
        }
    }
}

// ---------------- split-fp16 flash attention: grid (16 q-tiles, 64 bh), block 256 ----------------
__global__ __launch_bounds__(256) void attn_sp(const f16* __restrict__ qh, const f16* __restrict__ ql,
                                               const f16* __restrict__ vth, const f16* __restrict__ vtl,
                                               f16* __restrict__ oh, f16* __restrict__ ol) {
    const int qt = blockIdx.x;
    const int bh = blockIdx.y;
    const int b = bh >> 3, h = bh & 7;
    const int tid = threadIdx.x;
    const int wave = tid >> 6, lane = tid & 63;
    const int quad = lane >> 4, l15 = lane & 15;

    __shared__ __align__(16) f16 Ph[4][16][80];
    __shared__ __align__(16) f16 Pl[4][16][80];

    const size_t tq = (size_t)b * 1024 + qt * 64 + wave * 16 + l15;
    f16x8 qh0 = *(const f16x8*)&qh[tq * 1536 + h * 64 + quad * 8];
    f16x8 qh1 = *(const f16x8*)&qh[tq * 1536 + h * 64 + 32 + quad * 8];
    f16x8 ql0 = *(const f16x8*)&ql[tq * 1536 + h * 64 + quad * 8];
    f16x8 ql1 = *(const f16x8*)&ql[tq * 1536 + h * 64 + 32 + quad * 8];

    f32x4 ao[4] = {}, ao2[4] = {};
    float m_i[4] = {-INFINITY, -INFINITY, -INFINITY, -INFINITY};
    float l_i[4] = {0.f, 0.f, 0.f, 0.f};

    const f16* kbh = qh + (size_t)b * 1024 * 1536 + 512 + h * 64;
    const f16* kbl = ql + (size_t)b * 1024 * 1536 + 512 + h * 64;
    const f16* vbh = vth + (size_t)bh * 64 * 1024;
    const f16* vbl = vtl + (size_t)bh * 64 * 1024;

    for (int kv0 = 0; kv0 < 1024; kv0 += 64) {
        f32x4 sa[4] = {}, sa2[4] = {};
#pragma unroll
        for (int ni = 0; ni < 4; ni++) {
            size_t kro = (size_t)(kv0 + ni*16 + l15) * 1536;
            f16x8 kh0 = *(const f16x8*)&kbh[kro + quad * 8];
            f16x8 kh1 = *(const f16x8*)&kbh[kro + 32 + quad * 8];
            f16x8 kl0 = *(const f16x8*)&kbl[kro + quad * 8];
            f16x8 kl1 = *(const f16x8*)&kbl[kro + 32 + quad * 8];
            sa[ni]  = __builtin_amdgcn_mfma_f32_16x16x32_f16(qh0, kh0, sa[ni], 0, 0, 0);
            sa[ni]  = __builtin_amdgcn_mfma_f32_16x16x32_f16(qh1, kh1, sa[ni], 0, 0, 0);
            sa2[ni] = __builtin_amdgcn_mfma_f32_16x16x32_f16(qh0, kl0, sa2[ni], 0, 0, 0);
            sa2[ni] = __builtin_amdgcn_mfma_f32_16x16x32_f16(qh1, kl1, sa2[ni], 0, 0, 0);
            sa2[ni] = __builtin_amdgcn_mfma_f32_16x16x32_f16(ql0, kh0, sa2[ni], 0, 0, 0);
            sa2[ni] = __builtin_amdgcn_mfma_f32_16x16x32_f16(ql1, kh1, sa2[ni], 0, 0, 0);
        }
        float alpha[4];
#pragma unroll
        for (int r = 0; r < 4; r++) {
            float s0 = (sa[0][r] + sa2[0][r]*RCP2048) * 0.125f;
            float s1 = (sa[1][r] + sa2[1][r]*RCP2048) * 0.125f;
            float s2 = (sa[2][r] + sa2[2][r]*RCP2048) * 0.125f;
            float s3 = (sa[3][r] + sa2[3][r]*RCP2048) * 0.125f;
            float mx = fmaxf(fmaxf(s0, s1), fmaxf(s2, s3));
#pragma unroll
            for (int msk = 1; msk < 16; msk <<= 1) mx = fmaxf(mx, __shfl_xor(mx, msk));
            float mnew = fmaxf(m_i[r], mx);
            alpha[r] = __expf(m_i[r] - mnew);
            float p0 = __expf(s0 - mnew), p1 = __expf(s1 - mnew);
            float p2 = __expf(s2 - mnew), p3 = __expf(s3 - mnew);
            sa[0][r] = p0; sa[1][r] = p1; sa[2][r] = p2; sa[3][r] = p3;
            float sum = p0 + p1 + p2 + p3;
#pragma unroll
            for (int msk = 1; msk < 16; msk <<= 1) sum += __shfl_xor(sum, msk);
            l_i[r] = l_i[r] * alpha[r] + sum;
            m_i[r] = mnew;
        }
#pragma unroll
        for (int ni = 0; ni < 4; ni++)
#pragma unroll
            for (int r = 0; r < 4; r++) {
                f16 hh, ll; split_f(sa[ni][r], &hh, &ll);
                Ph[wave][quad*4 + r][ni*16 + l15] = hh;
                Pl[wave][quad*4 + r][ni*16 + l15] = ll;
            }
#pragma unroll
        for (int di = 0; di < 4; di++)
#pragma unroll
            for (int r = 0; r < 4; r++) { ao[di][r] *= alpha[r]; ao2[di][r] *= alpha[r]; }
        f16x8 pfh0 = *(const f16x8*)&Ph[wave][l15][quad * 8];
        f16x8 pfh1 = *(const f16x8*)&Ph[wave][l15][32 + quad * 8];
        f16x8 pfl0 = *(const f16x8*)&Pl[wave][l15][quad * 8];
        f16x8 pfl1 = *(const f16x8*)&Pl[wave][l15][32 + quad * 8];
#pragma unroll
        for (int di = 0; di < 4; di++) {
            size_t vro = (size_t)(di*16 + l15) * 1024 + kv0;
            f16x8 vh0 = *(const f16x8*)&vbh[vro + quad * 8];
            f16x8 vh1 = *(const f16x8*)&vbh[vro + 32 + quad * 8];
            f16x8 vl0 = *(const f16x8*)&vbl[vro + quad * 8];
            f16x8 vl1 = *(const f16x8*)&vbl[vro + 32 + quad * 8];
            ao[di]  = __builtin_amdgcn_mfma_f32_16x16x32_f16(pfh0, vh0, ao[di], 0, 0, 0);
            ao[di]  = __builtin_amdgcn_mfma_f32_16x16x32_f16(pfh1, vh1, ao[di], 0, 0, 0);
            ao2[di] = __builtin_amdgcn_mfma_f32_16x16x32_f16(pfh0, vl0, ao2[di], 0, 0, 0);
            ao2[di] = __builtin_amdgcn_mfma_f32_16x16x32_f16(pfh1, vl1, ao2[di], 0, 0, 0);
            ao2[di] = __builtin_amdgcn_mfma_f32_16x16x32_f16(pfl0, vh0, ao2[di], 0, 0, 0);
            ao2[di] = __builtin_amdgcn_mfma_f32_16x16x32_f16(pfl1, vh1, ao2[di], 0, 0, 0);
        }
    }
#pragma unroll
    for (int di = 0; di < 4; di++) {
#pragma unroll
        for (int r = 0; r < 4; r++) {
            size_t t = (size_t)b * 1024 + qt * 64 + wave * 16 + quad * 4 + r;
            float v = (ao[di][r] + ao2[di][r] * RCP2048) / l_i[r];
            f16 hh, ll; split_f(v, &hh, &ll);
            oh[t * 512 + h * 64 + di * 16 + l15] = hh;
            ol[t * 512 + h * 64 + di * 16 + l15] = ll;
        }
    }
}

// ---------------- gating (fp32, unchanged from round 2) ----------------
__global__ __launch_bounds__(64) void gating_k(const float* __restrict__ xn, const float* __restrict__ wg,
                                               int* __restrict__ top_i, float* __restrict__ top_g,
                                               int* __restrict__ counts) {
    int t = blockIdx.x, lane = threadIdx.x;
    const float* xr = xn + (size_t)t * 512;
    float acc[8] = {};
#pragma unroll
    for (int i = 0; i < 8; i++) {
        int d = lane + i*64;
        float xv = xr[d];
        const float* wrow = wg + (size_t)d * 8;
#pragma unroll
        for (int e = 0; e < 8; e++) acc[e] += xv * wrow[e];
    }
#pragma unroll
    for (int e = 0; e < 8; e++)
#pragma unroll
        for (int m = 32; m; m >>= 1) acc[e] += __shfl_xor(acc[e], m);
    if (lane == 0) {
        int e0 = 0; float v0 = acc[0];
        for (int e = 1; e < 8; e++) if (acc[e] > v0) { v0 = acc[e]; e0 = e; }
        int e1 = -1; float v1 = -INFINITY;
        for (int e = 0; e < 8; e++) if (e != e0 && acc[e] > v1) { v1 = acc[e]; e1 = e; }
        float g0 = 1.f / (1.f + expf(v1 - v0));
        top_i[2*t] = e0; top_i[2*t + 1] = e1;
        top_g[2*t] = g0; top_g[2*t + 1] = 1.f - g0;
        atomicAdd(&counts[e0], 1);
        atomicAdd(&counts[e1], 1);
    }
}

__global__ void zero_counts_k(int* counts) { if (threadIdx.x < 8) counts[threadIdx.x] = 0; }

__global__ void offsets_k(const int* __restrict__ counts, int* __restrict__ offs, int* __restrict__ cursor) {
    if (threadIdx.x == 0) {
        int o = 0;
        for (int e = 0; e < 8; e++) { offs[e] = o; cursor[e] = o; o += counts[e]; }
    }
}

__global__ __launch_bounds__(256) void scatter_k(const int* __restrict__ top_i, int* __restrict__ cursor,
                                                 int* __restrict__ assign_token, int* __restrict__ assign_slot) {
    int t = blockIdx.x * 256 + threadIdx.x;
#pragma unroll
    for (int k = 0; k < 2; k++) {
        int e = top_i[2*t + k];
        int pos = atomicAdd(&cursor[e], 1);
        assign_token[pos] = t;
        assign_slot[2*t + k] = pos;
    }
}

__global__ __launch_bounds__(64) void gather2_k(const f16* __restrict__ xh, const f16* __restrict__ xl,
                                                const int* __restrict__ assign_token,
                                                f16* __restrict__ oh, f16* __restrict__ ol) {
    int a = blockIdx.x, lane = threadIdx.x;
    int t = assign_token[a];
    ((uint4*)(oh + (size_t)a * 512))[lane] = ((const uint4*)(xh + (size_t)t * 512))[lane];
    ((uint4*)(ol + (size_t)a * 512))[lane] = ((const uint4*)(xl + (size_t)t * 512))[lane];
}

__global__ __launch_bounds__(64) void combine_k(float* __restrict__ x, const float* __restrict__ y,
                                                const int* __restrict__ assign_slot, const float* __restrict__ top_g) {
    int t = blockIdx.x, lane = threadIdx.x;
    int p0 = assign_slot[2*t], p1 = assign_slot[2*t + 1];
    float g0 = top_g[2*t], g1 = top_g[2*t + 1];
    float4* xr = (float4*)(x + (size_t)t * 512);
    const float4* y0 = (const float4*)(y + (size_t)p0 * 512);
    const float4* y1 = (const float4*)(y + (size_t)p1 * 512);
#pragma unroll
    for (int i = 0; i < 2; i++) {
        int idx = lane + i * 64;
        float4 a = xr[idx], c0 = y0[idx], c1 = y1[idx];
        a.x += g0*c0.x + g1*c1.x; a.y += g0*c0.y + g1*c1.y;
        a.z += g0*c0.z + g1*c1.z; a.w += g0*c0.w + g1*c1.w;
        xr[idx] = a;
    }
}

extern "C" void kernel_launch(void* const* d_in, const int* in_sizes, int n_in,
                              void* d_out, int out_size, void* d_ws, size_t ws_size,
                              hipStream_t stream) {
    const float* x_in = (const float*)d_in[0];
    const float* ln1w = (const float*)d_in[1];
    const float* ln1b = (const float*)d_in[2];
    const float* qkvw = (const float*)d_in[3];
    const float* outw = (const float*)d_in[4];
    const float* outb = (const float*)d_in[5];
    const float* ln2w = (const float*)d_in[6];
    const float* ln2b = (const float*)d_in[7];
    const float* wg   = (const float*)d_in[8];
    const float* ew1  = (const float*)d_in[9];
    const float* eb1  = (const float*)d_in[10];
    const float* ew2  = (const float*)d_in[11];
    const float* eb2  = (const float*)d_in[12];
    const float* flnw = (const float*)d_in[13];
    const float* flnb = (const float*)d_in[14];

    float* x = (float*)d_out;                         // residual [8192,512] f32

    char* ws = (char*)d_ws;
    float* xn32  = (float*)(ws + 0);                  // 16 MB
    f16*   xnh   = (f16*)(ws + 16*MB);                //  8 MB
    f16*   xnl   = (f16*)(ws + 24*MB);                //  8 MB
    f16*   qkTh  = (f16*)(ws + 32*MB);                //  1.5 MB
    f16*   qkTl  = (f16*)(ws + 34*MB);
    f16*   outTh = (f16*)(ws + 36*MB);                //  0.5 MB
    f16*   outTl = (f16*)(ws + 37*MB);
    f16*   w1Th  = (f16*)(ws + 38*MB);                // 16 MB [8][2048][512]
    f16*   w1Tl  = (f16*)(ws + 54*MB);
    f16*   w2Th  = (f16*)(ws + 70*MB);                // 16 MB [8][512][2048]
    f16*   w2Tl  = (f16*)(ws + 86*MB);
    char*  S     = ws + 102*MB;
    // attn phase
    f16*   qbh   = (f16*)(S + 0);                     // 24 MB [8192,1536]
    f16*   qbl   = (f16*)(S + 24*MB);
    f16*   vth   = (f16*)(S + 48*MB);                 //  8 MB [64][64][1024]
    f16*   vtl   = (f16*)(S + 56*MB);
    f16*   obh   = (f16*)(S + 64*MB);                 //  8 MB [8192,512]
    f16*   obl   = (f16*)(S + 72*MB);
    // moe phase (reuses S)
    f16*   xeh   = (f16*)(S + 0);                     // 16 MB [16384,512]
    f16*   xel   = (f16*)(S + 16*MB);
    f16*   hbh   = (f16*)(S + 32*MB);                 // 16 MB [16384,512] per H-slice
    f16*   hbl   = (f16*)(S + 48*MB);
    float* ybuf  = (float*)(S + 64*MB);               // 32 MB [16384,512]
    char*  SM    = ws + 198*MB;
    int*   top_i        = (int*)(SM + 0);
    float* top_g        = (float*)(SM + 65536);
    int*   assign_token = (int*)(SM + 131072);
    int*   assign_slot  = (int*)(SM + 196608);
    int*   counts       = (int*)(SM + 262144);
    int*   offs         = (int*)(SM + 262400);
    int*   cursor       = (int*)(SM + 262656);

    hipMemcpyAsync(x, x_in, (size_t)8192 * 512 * 4, hipMemcpyDeviceToDevice, stream);

    dim3 tb(32, 8);
    for (int l = 0; l < 4; l++) {
        const float* qkvw_l = qkvw + (size_t)l * 512 * 1536;
        const float* outw_l = outw + (size_t)l * 512 * 512;
        const float* ew1_l  = ew1  + (size_t)l * 8 * 512 * 2048;
        const float* ew2_l  = ew2  + (size_t)l * 8 * 2048 * 512;
        const float* eb1_l  = eb1  + (size_t)l * 8 * 2048;
        const float* eb2_l  = eb2  + (size_t)l * 8 * 512;

        // weight prep: transpose + split to fp16 hi/lo, [N,K] layout
        transpose_split_k<<<dim3(48, 16, 1), tb, 0, stream>>>(qkvw_l, qkTh, qkTl, 512, 1536, 0, 0);
        transpose_split_k<<<dim3(16, 16, 1), tb, 0, stream>>>(outw_l, outTh, outTl, 512, 512, 0, 0);
        transpose_split_k<<<dim3(64, 16, 8), tb, 0, stream>>>(ew1_l, w1Th, w1Tl, 512, 2048,
                                                              (long)512*2048, (long)512*2048);
        transpose_split_k<<<dim3(16, 64, 8), tb, 0, stream>>>(ew2_l, w2Th, w2Tl, 2048, 512,
                                                              (long)2048*512, (long)2048*512);

        // ---- attention ----
        ln_split_k<0><<<8192, 256, 0, stream>>>(x, ln1w + l*512, ln1b + l*512, nullptr, xnh, xnl);
        gemm_sp<0><<<dim3(64, 12, 1), 256, 0, stream>>>(xnh, xnl, 512, qkTh, qkTl, 512, nullptr,
                                                        qbh, qbl, 1536, 8192, 512,
                                                        nullptr, nullptr, 0, 0);
        transpose_v_k<<<dim3(32, 2, 64), tb, 0, stream>>>(qbh, vth);
        transpose_v_k<<<dim3(32, 2, 64), tb, 0, stream>>>(qbl, vtl);
        attn_sp<<<dim3(16, 64), 256, 0, stream>>>(qbh, qbl, vth, vtl, obh, obl);
        gemm_sp<1><<<dim3(64, 4, 1), 256, 0, stream>>>(obh, obl, 512, outTh, outTl, 512, outb + l*512,
                                                       x, nullptr, 512, 8192, 512,
                                                       nullptr, nullptr, 0, 0);

        // ---- MoE ----
        ln_split_k<1><<<8192, 256, 0, stream>>>(x, ln2w + l*512, ln2b + l*512, xn32, xnh, xnl);
        zero_counts_k<<<1, 64, 0, stream>>>(counts);
        gating_k<<<8192, 64, 0, stream>>>(xn32, wg + (size_t)l*512*8, top_i, top_g, counts);
        offsets_k<<<1, 1, 0, stream>>>(counts, offs, cursor);
        scatter_k<<<32, 256, 0, stream>>>(top_i, cursor, assign_token, assign_slot);
        gather2_k<<<16384, 64, 0, stream>>>(xnh, xnl, assign_token, xeh, xel);

        for (int s = 0; s < 4; s++) {
            const f16* b1h = w1Th + (size_t)s * 512 * 512;   // rows s*512.. of [2048,512]
            const f16* b1l = w1Tl + (size_t)s * 512 * 512;
            const f16* b2h = w2Th + (size_t)s * 512;         // k-cols s*512.. of [512,2048]
            const f16* b2l = w2Tl + (size_t)s * 512;
            gemm_sp<2><<<dim3(128, 4, 8), 256, 0, stream>>>(xeh, xel, 512, b1h, b1l, 512, eb1_l + s*512,
                                                            hbh, hbl, 512, 0, 512,
                                                            counts, offs, (long)2048*512, 2048);
            if (s == 0)
                gemm_sp<3><<<dim3(128, 4, 8), 256, 0, stream>>>(hbh, hbl, 512, b2h, b2l, 2048, eb2_l,
                                                                ybuf, nullptr, 512, 0, 512,
                                                                counts, offs, (long)512*2048, 512);
            else
                gemm_sp<4><<<dim3(128, 4, 8), 256, 0, stream>>>(hbh, hbl, 512, b2h, b2l, 2048, nullptr,
                                                                ybuf, nullptr, 512, 0, 512,
                                                                counts, offs, (long)512*2048, 512);
        }
        combine_k<<<8192, 64, 0, stream>>>(x, ybuf, assign_slot, top_g);
    }
    ln_k<<<8192, 256, 0, stream>>>(x, flnw, flnb, x);
}